// Round 12
// baseline (322.594 us; speedup 1.0000x reference)
//
#include <hip/hip_runtime.h>

// StructuredElmanCell via MFMA, split-precision (hi/lo) bf16 inputs.
// Wave owns a 16n x 16p H-tile; K=32 MFMA carries (Bhi*Xhi)+(Bhi*Xlo)+
// (Blo*Xhi)+(Blo*Xlo) across its 4 k-octets (validated R7+, absmax 64).
// R12: DUAL-CHAIN ILP. Occupancy is stuck at 1 wave/SIMD (R10: 2 waves/EU
// forces spill; R11: (256,1) never co-resides), so the x2 parallelism moves
// INSIDE the wave: each wave runs two independent time-halves of its tile
// (chain0: t in [0,544) from H0; chain1: t in [480,1024) from H=0 with
// 64-step contraction warmup, emits t>=544). The interleaved second chain
// fills the ~50% dependency-stall budget single-chain in-order issue left.
// GROUP=4 keeps registers bounded; barrier serves 2x4 step-equivalents.

namespace {
constexpr int T  = 1024;
constexpr int BS = 4;
constexpr int NH = 16;
constexpr int DS = 32;
constexpr int HD = 128;
constexpr int R  = 8;
constexpr int DI = NH * HD;              // 2048
constexpr int GROUP = 4;                 // steps per group per chain

// byte strides
constexpr unsigned B_T  = BS * NH * DS * R * 4;  // 65536 B per t
constexpr unsigned X_T  = BS * NH * HD * R * 4;  // 262144 B per t
constexpr unsigned A_T4 = BS * NH * 4;           // 256 B per t
constexpr unsigned ZO_T = BS * DI * 4;           // 32768 B per t (z and out)
constexpr unsigned B_G  = B_T * GROUP;
constexpr unsigned X_G  = X_T * GROUP;
constexpr unsigned A_G  = A_T4 * GROUP;
constexpr unsigned ZO_G = ZO_T * GROUP;

constexpr int STEPS   = 544;             // per chain
constexpr int NG      = STEPS / GROUP;   // 136 groups per chain
constexpr int TB1     = T - STEPS;       // 480 = chain1 t_begin
constexpr int EMIT1_G = (544 - TB1) / GROUP;  // 16 warmup groups for chain1

constexpr float LOG2E = 1.4426950408889634f;

typedef __attribute__((ext_vector_type(8))) short bf16x8;
typedef __attribute__((ext_vector_type(4))) float f32x4;
typedef __attribute__((ext_vector_type(4))) unsigned u32x4;

__device__ __forceinline__ float fast_exp(float x) {
    return __builtin_amdgcn_exp2f(x * LOG2E);
}
__device__ __forceinline__ float fast_silu(float x) {
    return x * __builtin_amdgcn_rcpf(1.0f + __builtin_amdgcn_exp2f(x * -LOG2E));
}
__device__ __forceinline__ float4 ld4(const void* p, unsigned off) {
    return *(const float4*)((const char*)p + off);
}
__device__ __forceinline__ float ld1(const void* p, unsigned off) {
    return *(const float*)((const char*)p + off);
}

// bf16-pair pack: low16 = sel(a), high16 = sel(b); hi = top-16 truncation,
// lo = exact fp32 remainder truncated to bf16.
__device__ __forceinline__ unsigned pack_pair(float a, float b, bool useHi) {
    unsigned ua = __float_as_uint(a), ub = __float_as_uint(b);
    unsigned hi = __builtin_amdgcn_perm(ub, ua, 0x07060302u);
    float la = a - __uint_as_float(ua & 0xffff0000u);   // exact
    float lb = b - __uint_as_float(ub & 0xffff0000u);
    unsigned lo = __builtin_amdgcn_perm(__float_as_uint(lb),
                                        __float_as_uint(la), 0x07060302u);
    return useHi ? hi : lo;
}
__device__ __forceinline__ u32x4 pack_frag(const float4& v0, const float4& v1,
                                           bool useHi) {
    u32x4 u;
    u.x = pack_pair(v0.x, v0.y, useHi);
    u.y = pack_pair(v0.z, v0.w, useHi);
    u.z = pack_pair(v1.x, v1.y, useHi);
    u.w = pack_pair(v1.z, v1.w, useHi);
    return u;
}

// ---------------- pass 0: alpha = 1/(2+exp(ar+ab)) == sigmoid(-softplus) ---
__global__ __launch_bounds__(256)
void alpha_kernel(const float* __restrict__ ar_, const float* __restrict__ ab_,
                  float* __restrict__ alpha_) {
    int i = blockIdx.x * 256 + threadIdx.x;          // [T,BS,NH] flat
    float v = ar_[i] + ab_[i & (NH - 1)];
    alpha_[i] = __builtin_amdgcn_rcpf(2.0f + fast_exp(v));
}

// ---------------- pass 1: MFMA scan, dual-chain ----------------------------
template<bool PRE>
__global__ __launch_bounds__(256, 1)
void elman_mfma_kernel(const float* __restrict__ B_,
                       const float* __restrict__ X_,
                       const float* __restrict__ a_,   // PRE? alpha : alpha_raw
                       const float* __restrict__ ab_,
                       const float* __restrict__ z_,
                       const float* __restrict__ H0_,
                       float* __restrict__ out_,
                       float* __restrict__ Hf_)
{
    __shared__ float ybuf[2][2][8][9][16];  // [parity][pcl][chain*4+stage][src+pad][p]

    const int lane = threadIdx.x & 63;
    const int W    = blockIdx.x * 4 + (threadIdx.x >> 6); // tile 0..1023
    const int nc   = W & 1;
    const int pc   = (W >> 1) & 7;
    const int bh   = W >> 4;
    const int h    = bh & (NH - 1);
    const int b    = bh >> 4;
    const int n0   = nc * 16;
    const int p0   = pc * 16;
    const int pcl  = pc & 1;
    const int l15  = lane & 15;
    const int sl   = lane >> 4;          // 0..3
    const int st   = nc * 4 + sl;        // lane's gate slot: chain=nc, stage=sl

    const bool useBhi = (lane < 32);
    const bool useXhi = ((lane & 16) == 0);

    const unsigned hoff = (unsigned)bh * 4096u
                        + (unsigned)(n0 + sl * 4) * 128u
                        + (unsigned)(p0 + l15);
    f32x4 Hc0, Hc1;
    Hc0.x = H0_[hoff];       Hc0.y = H0_[hoff + 128];
    Hc0.z = H0_[hoff + 256]; Hc0.w = H0_[hoff + 384];
    Hc1.x = 0.f; Hc1.y = 0.f; Hc1.z = 0.f; Hc1.w = 0.f;  // warmup from zero

    const float abv = PRE ? 0.0f : ab_[h];

    // byte offsets off SGPR bases
    const unsigned bBb = ((unsigned)bh * (DS * R) + (unsigned)(n0 + l15) * R) * 4u;
    const unsigned bXb = ((unsigned)bh * (HD * R) + (unsigned)(p0 + l15) * R) * 4u;
    unsigned bB0 = bBb;
    unsigned bB1 = bBb + (unsigned)TB1 * B_T;
    unsigned bX0 = bXb;
    unsigned bX1 = bXb + (unsigned)TB1 * X_T;
    // lanes 0-3: chain0 stages 0-3; lanes 4-7: chain1 stages 0-3 (dup above)
    unsigned bA  = ((unsigned)(lane & 3) + (unsigned)((lane >> 2) & 1) * (unsigned)TB1)
                 * A_T4 + (unsigned)bh * 4u;
    unsigned bZ  = ((unsigned)b * DI + (unsigned)h * HD + (unsigned)(p0 + l15)) * 4u
                 + ((unsigned)(nc * TB1) + (unsigned)sl) * ZO_T;
    unsigned bO  = bZ;

    float4 r0B0[GROUP], r0B1[GROUP], r0X0[GROUP], r0X1[GROUP];
    float4 r1B0[GROUP], r1B1[GROUP], r1X0[GROUP], r1X1[GROUP];
    u32x4 P0A[GROUP], P0B[GROUP], P1A[GROUP], P1B[GROUP];
    u32x4 Q0A[GROUP], Q0B[GROUP], Q1A[GROUP], Q1B[GROUP];
    float py0[GROUP], py1[GROUP];
    float avA, avB, zvA, zvB;

    auto loadraw = [&]() {
        #pragma unroll
        for (int s = 0; s < GROUP; ++s) {
            r0B0[s] = ld4(B_, bB0 + (unsigned)s * B_T);
            r0B1[s] = ld4(B_, bB0 + (unsigned)s * B_T + 16u);
            r0X0[s] = ld4(X_, bX0 + (unsigned)s * X_T);
            r0X1[s] = ld4(X_, bX0 + (unsigned)s * X_T + 16u);
            r1B0[s] = ld4(B_, bB1 + (unsigned)s * B_T);
            r1B1[s] = ld4(B_, bB1 + (unsigned)s * B_T + 16u);
            r1X0[s] = ld4(X_, bX1 + (unsigned)s * X_T);
            r1X1[s] = ld4(X_, bX1 + (unsigned)s * X_T + 16u);
        }
        bB0 += B_G; bB1 += B_G; bX0 += X_G; bX1 += X_G;
    };

    // prologue: raw g0 -> pack into P; raw g1 into ring; bB now at g2
    loadraw();
    avA = ld1(a_, bA); bA += A_G;
    zvA = ld1(z_, bZ); bZ += ZO_G;
    #pragma unroll
    for (int s = 0; s < GROUP; ++s) {
        P0A[s] = pack_frag(r0B0[s], r0B1[s], useBhi);
        P0B[s] = pack_frag(r0X0[s], r0X1[s], useXhi);
        P1A[s] = pack_frag(r1B0[s], r1B1[s], useBhi);
        P1B[s] = pack_frag(r1X0[s], r1X1[s], useXhi);
    }
    loadraw();

    auto step = [&](f32x4& H, const u32x4& af, const u32x4& bf,
                    float avC, int ln, float& py) {
        float ar = __int_as_float(
            __builtin_amdgcn_readlane(__float_as_int(avC), ln));
        float alpha = PRE ? ar
                          : __builtin_amdgcn_rcpf(2.0f + fast_exp(ar + abv));
        f32x4 c;
        c.x = alpha * H.x; c.y = alpha * H.y;
        c.z = alpha * H.z; c.w = alpha * H.w;
        f32x4 d = __builtin_amdgcn_mfma_f32_16x16x32_bf16(
            __builtin_bit_cast(bf16x8, af), __builtin_bit_cast(bf16x8, bf),
            c, 0, 0, 0);
        H.x = fast_silu(d.x); H.y = fast_silu(d.y);
        H.z = fast_silu(d.z); H.w = fast_silu(d.w);
        py = (H.x + H.y) + (H.z + H.w);
    };

    auto exchange = [&](int par, float zvC, bool emit1) {
        #pragma unroll
        for (int s = 0; s < GROUP; ++s) {
            ybuf[par][pcl][s][st][l15]     = py0[s];
            ybuf[par][pcl][4 + s][st][l15] = py1[s];
        }
        asm volatile("s_waitcnt lgkmcnt(0)" ::: "memory");
        __builtin_amdgcn_s_barrier();
        __builtin_amdgcn_sched_barrier(0);
        asm volatile("" ::: "memory");
        float y2 = 0.0f;
        #pragma unroll
        for (int k = 0; k < 8; ++k)
            y2 += ybuf[par][pcl][st][k][l15];
        float gt = y2 * fast_silu(zvC + y2);
        if (!nc || emit1) *(float*)((char*)out_ + bO) = gt;
        bO += ZO_G;
    };

    auto body = [&](u32x4 (&C0A)[GROUP], u32x4 (&C0B)[GROUP],
                    u32x4 (&C1A)[GROUP], u32x4 (&C1B)[GROUP],
                    u32x4 (&N0A)[GROUP], u32x4 (&N0B)[GROUP],
                    u32x4 (&N1A)[GROUP], u32x4 (&N1B)[GROUP],
                    float avC, float& avN, float zvC, float& zvN,
                    int par, bool refill, bool emit1) {
        avN = ld1(a_, bA); bA += A_G;
        zvN = ld1(z_, bZ); bZ += ZO_G;
        #pragma unroll
        for (int s = 0; s < GROUP; ++s) {
            step(Hc0, C0A[s], C0B[s], avC, s,     py0[s]);
            step(Hc1, C1A[s], C1B[s], avC, 4 + s, py1[s]);
            N0A[s] = pack_frag(r0B0[s], r0B1[s], useBhi);
            N0B[s] = pack_frag(r0X0[s], r0X1[s], useXhi);
            N1A[s] = pack_frag(r1B0[s], r1B1[s], useBhi);
            N1B[s] = pack_frag(r1X0[s], r1X1[s], useXhi);
            if (refill) {
                r0B0[s] = ld4(B_, bB0 + (unsigned)s * B_T);
                r0B1[s] = ld4(B_, bB0 + (unsigned)s * B_T + 16u);
                r0X0[s] = ld4(X_, bX0 + (unsigned)s * X_T);
                r0X1[s] = ld4(X_, bX0 + (unsigned)s * X_T + 16u);
                r1B0[s] = ld4(B_, bB1 + (unsigned)s * B_T);
                r1B1[s] = ld4(B_, bB1 + (unsigned)s * B_T + 16u);
                r1X0[s] = ld4(X_, bX1 + (unsigned)s * X_T);
                r1X1[s] = ld4(X_, bX1 + (unsigned)s * X_T + 16u);
            }
        }
        if (refill) { bB0 += B_G; bB1 += B_G; bX0 += X_G; bX1 += X_G; }
        exchange(par, zvC, emit1);
    };

    // main: ping-pong; refill g+2; groups 0..133 in the loop
    int g = 0;
    #pragma unroll 1
    for (int gg = 0; gg < (NG - 2) / 2; ++gg) {
        body(P0A, P0B, P1A, P1B, Q0A, Q0B, Q1A, Q1B,
             avA, avB, zvA, zvB, g & 1, true, g >= EMIT1_G); ++g;
        body(Q0A, Q0B, Q1A, Q1B, P0A, P0B, P1A, P1B,
             avB, avA, zvB, zvA, g & 1, true, g >= EMIT1_G); ++g;
    }
    // g = 134: pack g135 from ring, no refill
    body(P0A, P0B, P1A, P1B, Q0A, Q0B, Q1A, Q1B,
         avA, avB, zvA, zvB, g & 1, false, true); ++g;
    // g = 135: steps only from Q
    #pragma unroll
    for (int s = 0; s < GROUP; ++s) {
        step(Hc0, Q0A[s], Q0B[s], avB, s,     py0[s]);
        step(Hc1, Q1A[s], Q1B[s], avB, 4 + s, py1[s]);
    }
    exchange(1, zvB, true);

    // H_final [BS,NH,DS,HD] comes from chain1 (t=1023)
    Hf_[hoff]       = Hc1.x;
    Hf_[hoff + 128] = Hc1.y;
    Hf_[hoff + 256] = Hc1.z;
    Hf_[hoff + 384] = Hc1.w;
}
} // namespace

extern "C" void kernel_launch(void* const* d_in, const int* in_sizes, int n_in,
                              void* d_out, int out_size, void* d_ws, size_t ws_size,
                              hipStream_t stream) {
    const float* B_proj     = (const float*)d_in[0];
    const float* X_proj     = (const float*)d_in[1];
    const float* alpha_raw  = (const float*)d_in[2];
    const float* alpha_bias = (const float*)d_in[3];
    const float* z          = (const float*)d_in[4];
    const float* H0         = (const float*)d_in[5];

    float* out = (float*)d_out;                       // [T,BS,DI] then Hf
    float* Hf  = out + (size_t)T * BS * DI;

    const size_t alpha_bytes = (size_t)T * BS * NH * sizeof(float);
    if (ws_size >= alpha_bytes) {
        float* aw = (float*)d_ws;
        alpha_kernel<<<T * BS * NH / 256, 256, 0, stream>>>(alpha_raw, alpha_bias, aw);
        elman_mfma_kernel<true><<<256, 256, 0, stream>>>(
            B_proj, X_proj, aw, alpha_bias, z, H0, out, Hf);
    } else {
        elman_mfma_kernel<false><<<256, 256, 0, stream>>>(
            B_proj, X_proj, alpha_raw, alpha_bias, z, H0, out, Hf);
    }
}

// Round 13
// 255.817 us; speedup vs baseline: 1.2610x; 1.2610x over previous
//
#include <hip/hip_runtime.h>

// StructuredElmanCell via MFMA, split-precision (hi/lo) bf16 inputs.
// Wave owns a 16n x 16p H-tile in fp32 regs; K=32 MFMA carries
// (Bhi*Xhi)+(Bhi*Xlo)+(Blo*Xhi)+(Blo*Xlo) across its 4 k-octets.
// R13 = R8's exact structure (124 VGPR, no spill, validated absmax 64)
//     + time-split (half1 starts t=496 from H=0, 48-step contraction warmup,
//       emits t>=544 — validated R10/R11)
//     + __launch_bounds__(256,2).
// Evidence: 2-wave/SIMD co-residency happens iff VGPR<=128 (R10: 128->23.4%
// occupancy; R11: 160->12%). R8's code fits that budget natively; R10's
// didn't and spilled. In-wave ILP (R9 dual-set, R12 dual-chain) never moved
// the ~850cy/step wall -> the stall budget needs TLP, i.e. a second
// co-resident wave per SIMD.

namespace {
constexpr int T  = 1024;
constexpr int BS = 4;
constexpr int NH = 16;
constexpr int DS = 32;
constexpr int HD = 128;
constexpr int R  = 8;
constexpr int DI = NH * HD;                  // 2048
constexpr int GROUP = 8;

// element (float) strides per timestep
constexpr unsigned BF_T  = BS * NH * DS * R; // 16384
constexpr unsigned XF_T  = BS * NH * HD * R; // 65536
constexpr unsigned A_T   = BS * NH;          // 64
constexpr unsigned OUT_T = BS * DI;          // 8192 (z and out)

constexpr int SPLIT_T  = 544;                // half0 emits t<544
constexpr int WARM     = 48;                 // half1 warmup steps (6 groups)
constexpr int T_BEGIN1 = SPLIT_T - WARM;     // 496
constexpr int NG0      = SPLIT_T / GROUP;    // 68 groups
constexpr int NG1      = (T - T_BEGIN1) / GROUP; // 66 groups
constexpr int EMIT1    = WARM / GROUP;       // 6 warmup groups

constexpr float LOG2E = 1.4426950408889634f;

typedef __attribute__((ext_vector_type(8))) short bf16x8;
typedef __attribute__((ext_vector_type(4))) float f32x4;
typedef __attribute__((ext_vector_type(4))) unsigned u32x4;

__device__ __forceinline__ float fast_exp(float x) {
    return __builtin_amdgcn_exp2f(x * LOG2E);
}
__device__ __forceinline__ float fast_silu(float x) {
    return x * __builtin_amdgcn_rcpf(1.0f + __builtin_amdgcn_exp2f(x * -LOG2E));
}

// bf16-pair pack: low16 = sel(a), high16 = sel(b); hi = top-16 truncation,
// lo = exact fp32 remainder truncated to bf16.
__device__ __forceinline__ unsigned pack2_sel(float a, float b, bool hi) {
    unsigned ba = __float_as_uint(a), bb = __float_as_uint(b);
    float ha = __uint_as_float(ba & 0xffff0000u);
    float hb = __uint_as_float(bb & 0xffff0000u);
    float va = hi ? ha : (a - ha);       // a - ha is EXACT in fp32
    float vb = hi ? hb : (b - hb);
    return __builtin_amdgcn_perm(__float_as_uint(vb), __float_as_uint(va),
                                 0x07060302u);
}

// ---------------- pass 0: alpha = 1/(2+exp(ar+ab)) == sigmoid(-softplus) ---
__global__ __launch_bounds__(256)
void alpha_kernel(const float* __restrict__ ar_, const float* __restrict__ ab_,
                  float* __restrict__ alpha_) {
    int i = blockIdx.x * 256 + threadIdx.x;          // [T,BS,NH] flat
    float v = ar_[i] + ab_[i & (NH - 1)];
    alpha_[i] = __builtin_amdgcn_rcpf(2.0f + fast_exp(v));
}

// ---------------- pass 1: MFMA scan, time-split ----------------------------
template<bool PRE>
__global__ __launch_bounds__(256, 2)
void elman_mfma_kernel(const float* __restrict__ B_,
                       const float* __restrict__ X_,
                       const float* __restrict__ a_,   // PRE? alpha : alpha_raw
                       const float* __restrict__ ab_,
                       const float* __restrict__ z_,
                       const float* __restrict__ H0_,
                       float* __restrict__ out_,
                       float* __restrict__ Hf_)
{
    __shared__ float ybuf[2][2][GROUP][16];  // [parity][pcl][stage][16 p]

    const int half = blockIdx.x >> 8;        // 0: t<544, 1: t>=496
    const int blk  = blockIdx.x & 255;
    const int lane = threadIdx.x & 63;
    const int W    = blk * 4 + (threadIdx.x >> 6); // tile 0..1023
    const int nc   = W & 1;            // n-chunk (0: n 0..15, 1: n 16..31)
    const int pc   = (W >> 1) & 7;     // p-chunk of 16
    const int bh   = W >> 4;           // 0..63
    const int h    = bh & (NH - 1);
    const int b    = bh >> 4;
    const int n0   = nc * 16;
    const int p0   = pc * 16;
    const int pcl  = pc & 1;
    const int l15  = lane & 15;
    const bool ld  = lane < 16;

    const int t_begin   = half ? T_BEGIN1 : 0;
    const int ngroups   = half ? NG1 : NG0;
    const int emit_from = half ? EMIT1 : 0;

    // lane group g = lane>>4 carries one K-octet of the K=32 contraction.
    const bool useBhi = (lane < 32);
    const bool useXhi = ((lane & 16) == 0);

    // H[i] at n = n0 + (lane>>4)*4 + i, p = p0 + l15 (C/D layout)
    const unsigned hoff = (unsigned)bh * 4096u
                        + (unsigned)(n0 + (lane >> 4) * 4) * 128u
                        + (unsigned)(p0 + l15);
    f32x4 H;
    if (half) {
        H.x = 0.f; H.y = 0.f; H.z = 0.f; H.w = 0.f;   // contraction warmup
    } else {
        H.x = H0_[hoff];       H.y = H0_[hoff + 128];
        H.z = H0_[hoff + 256]; H.w = H0_[hoff + 384];
    }

    const float abv = PRE ? 0.0f : ab_[h];

    // element offsets off SGPR bases, shifted to t_begin
    unsigned oB = (unsigned)bh * (DS * R) + (unsigned)(n0 + l15) * R
                + (unsigned)t_begin * BF_T;
    unsigned oX = (unsigned)bh * (HD * R) + (unsigned)(p0 + l15) * R
                + (unsigned)t_begin * XF_T;
    unsigned oA = (unsigned)bh + (unsigned)t_begin * A_T;
    unsigned oZ = (unsigned)b * DI + (unsigned)h * HD + (unsigned)(p0 + l15)
                + (unsigned)t_begin * OUT_T;
    unsigned oO = oZ;

    float4 sB0[GROUP], sB1[GROUP], sX0[GROUP], sX1[GROUP];
    float  sAl[GROUP], sZ[GROUP];
    #pragma unroll
    for (int s = 0; s < GROUP; ++s) {
        sB0[s] = *(const float4*)(B_ + oB + (unsigned)s * BF_T);
        sB1[s] = *(const float4*)(B_ + oB + (unsigned)s * BF_T + 4u);
        sX0[s] = *(const float4*)(X_ + oX + (unsigned)s * XF_T);
        sX1[s] = *(const float4*)(X_ + oX + (unsigned)s * XF_T + 4u);
        sAl[s] = a_[oA + (unsigned)s * A_T];
        sZ[s]  = z_[oZ + (unsigned)s * OUT_T];
    }
    oB += (unsigned)GROUP * BF_T;
    oX += (unsigned)GROUP * XF_T;
    oA += (unsigned)GROUP * A_T;
    oZ += (unsigned)GROUP * OUT_T;

    auto build = [](const float4& v0, const float4& v1, bool hi) -> bf16x8 {
        u32x4 u;
        u.x = pack2_sel(v0.x, v0.y, hi);
        u.y = pack2_sel(v0.z, v0.w, hi);
        u.z = pack2_sel(v1.x, v1.y, hi);
        u.w = pack2_sel(v1.z, v1.w, hi);
        return __builtin_bit_cast(bf16x8, u);
    };

    // one recurrence step; returns this wave's 16-row partial y (all lanes)
    auto do_step = [&](int s) -> float {
        bf16x8 af = build(sB0[s], sB1[s], useBhi);
        bf16x8 bf = build(sX0[s], sX1[s], useXhi);

        float ar    = __int_as_float(
                          __builtin_amdgcn_readfirstlane(__float_as_int(sAl[s])));
        float alpha = PRE ? ar
                          : __builtin_amdgcn_rcpf(2.0f + fast_exp(ar + abv));

        f32x4 c;
        c.x = alpha * H.x; c.y = alpha * H.y;
        c.z = alpha * H.z; c.w = alpha * H.w;
        f32x4 d = __builtin_amdgcn_mfma_f32_16x16x32_bf16(af, bf, c, 0, 0, 0);

        H.x = fast_silu(d.x); H.y = fast_silu(d.y);
        H.z = fast_silu(d.z); H.w = fast_silu(d.w);

        float y = (H.x + H.y) + (H.z + H.w);
        y += __shfl_xor(y, 16, 64);
        y += __shfl_xor(y, 32, 64);
        return y;
    };

    float yb[GROUP], zb[GROUP];

    // exchange + gate + store for one finished group (parity gp, out base oOg)
    auto exchange = [&](int gp, unsigned oOg) {
        if (nc) {
            if (ld) {
                #pragma unroll
                for (int s = 0; s < GROUP; ++s)
                    ybuf[gp][pcl][s][l15] = yb[s];
            }
            asm volatile("s_waitcnt lgkmcnt(0)" ::: "memory");
        }
        __builtin_amdgcn_s_barrier();
        __builtin_amdgcn_sched_barrier(0);
        asm volatile("" ::: "memory");
        if (!nc && ld) {
            #pragma unroll
            for (int s = 0; s < GROUP; ++s) {
                float y2 = yb[s] + ybuf[gp][pcl][s][l15];
                float g  = y2 * fast_silu(zb[s] + y2);
                out_[oOg + (unsigned)s * OUT_T] = g;
            }
        }
    };

    int gp = 0;
    #pragma unroll 1
    for (int g = 0; g < ngroups - 1; ++g) {
        #pragma unroll
        for (int s = 0; s < GROUP; ++s) {
            zb[s] = sZ[s];                 // preserve before refill
            yb[s] = do_step(s);
            // refill stage s with group g+1
            sB0[s] = *(const float4*)(B_ + oB + (unsigned)s * BF_T);
            sB1[s] = *(const float4*)(B_ + oB + (unsigned)s * BF_T + 4u);
            sX0[s] = *(const float4*)(X_ + oX + (unsigned)s * XF_T);
            sX1[s] = *(const float4*)(X_ + oX + (unsigned)s * XF_T + 4u);
            sAl[s] = a_[oA + (unsigned)s * A_T];
            sZ[s]  = z_[oZ + (unsigned)s * OUT_T];
        }
        if (g >= emit_from) exchange(gp, oO);   // block-uniform skip in warmup
        gp ^= 1;
        oB += (unsigned)GROUP * BF_T;
        oX += (unsigned)GROUP * XF_T;
        oA += (unsigned)GROUP * A_T;
        oZ += (unsigned)GROUP * OUT_T;
        oO += (unsigned)GROUP * OUT_T;
    }
    // tail group: consume, no refill
    #pragma unroll
    for (int s = 0; s < GROUP; ++s) {
        zb[s] = sZ[s];
        yb[s] = do_step(s);
    }
    exchange(gp, oO);

    // H_final [BS,NH,DS,HD]: t=1023 lives in half1
    if (half) {
        Hf_[hoff]       = H.x;
        Hf_[hoff + 128] = H.y;
        Hf_[hoff + 256] = H.z;
        Hf_[hoff + 384] = H.w;
    }
}
} // namespace

extern "C" void kernel_launch(void* const* d_in, const int* in_sizes, int n_in,
                              void* d_out, int out_size, void* d_ws, size_t ws_size,
                              hipStream_t stream) {
    const float* B_proj     = (const float*)d_in[0];
    const float* X_proj     = (const float*)d_in[1];
    const float* alpha_raw  = (const float*)d_in[2];
    const float* alpha_bias = (const float*)d_in[3];
    const float* z          = (const float*)d_in[4];
    const float* H0         = (const float*)d_in[5];

    float* out = (float*)d_out;                       // [T,BS,DI] then Hf
    float* Hf  = out + (size_t)T * BS * DI;

    const size_t alpha_bytes = (size_t)T * BS * NH * sizeof(float);
    if (ws_size >= alpha_bytes) {
        float* aw = (float*)d_ws;
        alpha_kernel<<<T * BS * NH / 256, 256, 0, stream>>>(alpha_raw, alpha_bias, aw);
        elman_mfma_kernel<true><<<512, 256, 0, stream>>>(
            B_proj, X_proj, aw, alpha_bias, z, H0, out, Hf);
    } else {
        elman_mfma_kernel<false><<<512, 256, 0, stream>>>(
            B_proj, X_proj, alpha_raw, alpha_bias, z, H0, out, Hf);
    }
}